// Round 12
// baseline (803.630 us; speedup 1.0000x reference)
//
#include <hip/hip_runtime.h>

#define N_NODES 50000
#define NE      500000
#define HIDD    128
#define TDIM    32

__device__ __forceinline__ float leaky(float z) { return z >= 0.f ? z : 0.2f * z; }

// Per-direction pointer bundle (passed by value to kernels).
struct DirP {
    const float *xsrc, *xdst, *Ws, *Wd, *Wv, *att, *tfeat, *Wt;
    const int* ei;
};

// ---------------------------------------------------------------------------
// R12 GEMM core (unchanged from R11): 128 rows/block, 8x8 tile/thread,
// K chunked by 32, both operands in LDS.
//  * W even/odd-quad split (conflicts 4.8M -> 0.6M): wa = wl[k][c0>>1],
//    wb = wl[k][64+(c0>>1)] — 16B-stride lane addrs (free) vs 32B (4-way).
//  * No register prefetch (R10: spilled, WRITE 26.5->76 MB).
//  * Plain __launch_bounds__(256) (R7: min-waves arg clamps VGPR -> spill).
// X swizzle: row r quad c4 at phys (c4 ^ ((r>>3)&7)); read quad (kq^(g&7)).
// R12 NEW: each phase launches BOTH directions in one grid (dir from
// blockIdx) when workspace permits — 12 dispatches -> 9, double grid depth,
// amortized ramp/drain. Runtime ws_size check falls back to the R11
// sequential schedule (dir=0 launches, single buffers) — no regression risk.
// ---------------------------------------------------------------------------
__device__ __forceinline__ void stage_x32(float (*xs)[32],
                                          const float* __restrict__ x,
                                          int nb, int kc, int t, int bound)
{
    #pragma unroll
    for (int i = 0; i < 4; ++i) {
        int idx = t + i * 256;              // 0..1023 quads
        int row = idx >> 3, c4 = idx & 7;
        int col = (c4 ^ ((row >> 3) & 7)) << 2;
        float4 v = make_float4(0.f, 0.f, 0.f, 0.f);
        if (nb + row < bound)
            v = *(const float4*)&x[(long)(nb + row) * HIDD + kc * 32 + c4 * 4];
        *(float4*)&xs[row][col] = v;
    }
}

__device__ __forceinline__ void stage_w32(float (*wl)[HIDD],
                                          const float* __restrict__ W,
                                          int kc, int t)
{
    #pragma unroll
    for (int i = 0; i < 4; ++i) {
        int idx = t + i * 256;              // 0..1023 quads
        int row = idx >> 5, c4 = idx & 31;
        int p = ((c4 & 1) << 4) | (c4 >> 1);   // even/odd quad split
        *(float4*)&wl[row][p * 4] =
            *(const float4*)&W[(long)(kc * 32 + row) * HIDD + c4 * 4];
    }
}

__device__ __forceinline__ void gemm_chunk(const float (*xs)[32],
                                           const float (*wl)[HIDD],
                                           int g, int c0, float acc[8][8])
{
    const int wq = c0 >> 1;                 // phys float offset of even quad
    #pragma unroll 1
    for (int kq = 0; kq < 8; ++kq) {
        float4 xv[8];
        const int col = ((kq ^ (g & 7)) << 2);
        #pragma unroll
        for (int nn = 0; nn < 8; ++nn)
            xv[nn] = *(const float4*)&xs[g * 8 + nn][col];
        #pragma unroll
        for (int kk = 0; kk < 4; ++kk) {
            const float4 wa = *(const float4*)&wl[kq * 4 + kk][wq];
            const float4 wb = *(const float4*)&wl[kq * 4 + kk][64 + wq];
            const float wv[8] = {wa.x, wa.y, wa.z, wa.w, wb.x, wb.y, wb.z, wb.w};
            #pragma unroll
            for (int nn = 0; nn < 8; ++nn) {
                const float xk = (kk == 0) ? xv[nn].x : (kk == 1) ? xv[nn].y
                               : (kk == 2) ? xv[nn].z : xv[nn].w;
                #pragma unroll
                for (int j = 0; j < 8; ++j) acc[nn][j] += xk * wv[j];
            }
        }
    }
}

// Per-head attention reduction: p = sum_c leaky(proj[c])*att[h][c&31],
// reduced over the 4 threads (q&3) sharing head h. Writer: q%4==0.
__device__ __forceinline__ void att_reduce_store(
    float acc[8][8], const float* __restrict__ att, int off,
    int nb, int g, int q, int h, float* __restrict__ outp)
{
    const float* ap = att + h * 96 + off + 8 * (q & 3);
    const float4 A0 = *(const float4*)ap, A1 = *(const float4*)(ap + 4);
    const float av[8] = {A0.x, A0.y, A0.z, A0.w, A1.x, A1.y, A1.z, A1.w};
    #pragma unroll
    for (int nn = 0; nn < 8; ++nn) {
        float p = 0.f;
        #pragma unroll
        for (int j = 0; j < 8; ++j) p += leaky(acc[nn][j]) * av[j];
        p += __shfl_down(p, 2, 4);
        p += __shfl_down(p, 1, 4);
        const int node = nb + g * 8 + nn;
        if ((q & 3) == 0 && node < N_NODES) outp[node * 4 + h] = p;
    }
}

// ---------------------------------------------------------------------------
// Kernel A: per-node projections (sj, si, V). Grid = half (seq) or 2*half.
// Within a dir: block bi -> m = bi%3 in {Ws->sj, Wv->V, Wd->si}, b = bi/3.
// dir=1 blocks offset sj/si/V by one dir-stride (merged path only).
// ---------------------------------------------------------------------------
__global__ __launch_bounds__(256) void node_proj2_kernel(
    DirP P0, DirP P1,
    float* __restrict__ sj, float* __restrict__ si, float* __restrict__ V,
    int half)
{
    __shared__ float xs[128][32];         // 16 KB
    __shared__ float wl[32][HIDD];        // 16 KB
    int bi = blockIdx.x;
    const int dir = bi >= half;
    bi -= dir * half;
    const DirP& P = dir ? P1 : P0;
    sj += (long)dir * N_NODES * 4;
    si += (long)dir * N_NODES * 4;
    V  += (long)dir * N_NODES * HIDD;

    const int m = bi % 3;                 // 0:Ws->sj 1:Wv->V 2:Wd->si
    const int b = bi / 3;
    const int t = threadIdx.x;
    const int g = t >> 4, q = t & 15;
    const int c0 = q * 8, h = q >> 2;
    const int nb = b * 128;

    const float* x = (m == 2) ? P.xdst : P.xsrc;
    const float* W = (m == 0) ? P.Ws : (m == 1) ? P.Wv : P.Wd;

    float acc[8][8];
    #pragma unroll
    for (int a = 0; a < 8; ++a)
        #pragma unroll
        for (int bb = 0; bb < 8; ++bb) acc[a][bb] = 0.f;

    #pragma unroll 1
    for (int kc = 0; kc < 4; ++kc) {
        stage_x32(xs, x, nb, kc, t, N_NODES);
        stage_w32(wl, W, kc, t);
        __syncthreads();
        gemm_chunk(xs, wl, g, c0, acc);
        __syncthreads();
    }

    if (m == 1) {
        #pragma unroll
        for (int nn = 0; nn < 8; ++nn) {
            const int node = nb + g * 8 + nn;
            if (node < N_NODES) {
                *(float4*)&V[(long)node * HIDD + c0] =
                    make_float4(acc[nn][0], acc[nn][1], acc[nn][2], acc[nn][3]);
                *(float4*)&V[(long)node * HIDD + c0 + 4] =
                    make_float4(acc[nn][4], acc[nn][5], acc[nn][6], acc[nn][7]);
            }
        }
    } else if (m == 0) {
        att_reduce_store(acc, P.att, 0, nb, g, q, h, sj);
    } else {
        att_reduce_store(acc, P.att, 32, nb, g, q, h, si);
    }
}

// ---------------------------------------------------------------------------
// CSR build (R6): both directions in one pass each.
// ---------------------------------------------------------------------------
__global__ __launch_bounds__(256) void count2_kernel(
    const int* __restrict__ ed0, const int* __restrict__ ed1,
    int* __restrict__ cnt)
{
    const int EB = (NE + 255) / 256;
    const int b = blockIdx.x;
    const int dir = b >= EB;
    const int e = (b - dir * EB) * 256 + threadIdx.x;
    const int* ed = dir ? ed1 : ed0;
    if (e < NE) atomicAdd(&cnt[dir * N_NODES + ed[e]], 1);
}

#define SCAN_T 1024
#define SCAN_CHUNK 49
__global__ __launch_bounds__(1024) void scan2_kernel(
    const int* __restrict__ cnt, int* __restrict__ rowptr)
{
    __shared__ int part[SCAN_T];
    const int dir = blockIdx.x;
    const int* c = cnt + dir * N_NODES;
    int* rp = rowptr + dir * (N_NODES + 8);
    const int t = threadIdx.x;
    const int b = t * SCAN_CHUNK;
    const int e = min(b + SCAN_CHUNK, N_NODES);
    int s = 0;
    for (int i = b; i < e; ++i) s += c[i];
    part[t] = s;
    __syncthreads();
    for (int off = 1; off < SCAN_T; off <<= 1) {
        int v = (t >= off) ? part[t - off] : 0;
        __syncthreads();
        part[t] += v;
        __syncthreads();
    }
    int run = (t > 0) ? part[t - 1] : 0;
    for (int i = b; i < e; ++i) { rp[i] = run; run += c[i]; }
    if (t == SCAN_T - 1) rp[N_NODES] = part[SCAN_T - 1];
}

__global__ __launch_bounds__(256) void scatter2_kernel(
    const int* __restrict__ ed0, const int* __restrict__ ed1,
    const int* __restrict__ rowptr, int* __restrict__ cursor,
    int* __restrict__ eord)
{
    const int EB = (NE + 255) / 256;
    const int b = blockIdx.x;
    const int dir = b >= EB;
    const int e = (b - dir * EB) * 256 + threadIdx.x;
    if (e < NE) {
        const int* ed = dir ? ed1 : ed0;
        const int d = ed[e];
        const int pos = rowptr[dir * (N_NODES + 8) + d]
                      + atomicAdd(&cursor[dir * N_NODES + d], 1);
        eord[dir * NE + pos] = e;
    }
}

// ---------------------------------------------------------------------------
// Kernel B: per-edge logits + exp. Wt staged once (even/odd swizzle).
// Register-tiled GEMM: 128 edges/block, 8 edges x 8 cols per thread, K=32.
// ---------------------------------------------------------------------------
__global__ __launch_bounds__(256, 4) void edge_logits2_kernel(
    DirP P0, DirP P1,
    const float* __restrict__ sj, const float* __restrict__ si,
    float* __restrict__ exbuf, int half)
{
    __shared__ float ts[128][TDIM];       // 16 KB
    __shared__ float wt[TDIM][HIDD];      // 16 KB
    int bi = blockIdx.x;
    const int dir = bi >= half;
    bi -= dir * half;
    const DirP& P = dir ? P1 : P0;
    sj    += (long)dir * N_NODES * 4;
    si    += (long)dir * N_NODES * 4;
    exbuf += (long)dir * NE * 4;

    const int t = threadIdx.x;
    const int g = t >> 4, q = t & 15;
    const int c0 = q * 8, h = q >> 2;
    const int wq = c0 >> 1;
    const int eb = bi * 128;

    #pragma unroll
    for (int i = 0; i < 4; ++i) {
        int idx = t + i * 256;
        int row = idx >> 3, c4 = idx & 7;
        int col = (c4 ^ ((row >> 3) & 7)) << 2;
        float4 v = make_float4(0.f, 0.f, 0.f, 0.f);
        if (eb + row < NE)
            v = *(const float4*)&P.tfeat[(long)(eb + row) * TDIM + c4 * 4];
        *(float4*)&ts[row][col] = v;
    }
    stage_w32(wt, P.Wt, 0, t);
    __syncthreads();

    float acc[8][8];
    #pragma unroll
    for (int a = 0; a < 8; ++a)
        #pragma unroll
        for (int b = 0; b < 8; ++b) acc[a][b] = 0.f;

    #pragma unroll 1
    for (int k4 = 0; k4 < 8; ++k4) {
        float4 xv[8];
        const int col = ((k4 ^ (g & 7)) << 2);
        #pragma unroll
        for (int nn = 0; nn < 8; ++nn)
            xv[nn] = *(const float4*)&ts[g * 8 + nn][col];
        #pragma unroll
        for (int kk = 0; kk < 4; ++kk) {
            const float4 wa = *(const float4*)&wt[k4 * 4 + kk][wq];
            const float4 wb = *(const float4*)&wt[k4 * 4 + kk][64 + wq];
            const float wv[8] = {wa.x, wa.y, wa.z, wa.w, wb.x, wb.y, wb.z, wb.w};
            #pragma unroll
            for (int nn = 0; nn < 8; ++nn) {
                const float xk = (kk == 0) ? xv[nn].x : (kk == 1) ? xv[nn].y
                               : (kk == 2) ? xv[nn].z : xv[nn].w;
                #pragma unroll
                for (int j = 0; j < 8; ++j) acc[nn][j] += xk * wv[j];
            }
        }
    }

    const float* ap = P.att + h * 96 + 64 + 8 * (q & 3);
    const float4 A0 = *(const float4*)ap, A1 = *(const float4*)(ap + 4);
    const float av[8] = {A0.x, A0.y, A0.z, A0.w, A1.x, A1.y, A1.z, A1.w};
    float st[8];
    #pragma unroll
    for (int nn = 0; nn < 8; ++nn) {
        float p = 0.f;
        #pragma unroll
        for (int j = 0; j < 8; ++j) p += leaky(acc[nn][j]) * av[j];
        p += __shfl_down(p, 2, 4);
        p += __shfl_down(p, 1, 4);
        st[nn] = p;
    }
    if ((q & 3) == 0) {
        #pragma unroll
        for (int nn = 0; nn < 8; ++nn) {
            const int e = eb + g * 8 + nn;
            if (e < NE) {
                const int src = P.ei[e], dst = P.ei[NE + e];
                exbuf[e * 4 + h] =
                    __expf(sj[src * 4 + h] + si[dst * 4 + h] + st[nn]);
            }
        }
    }
}

// ---------------------------------------------------------------------------
// Kernel C: CSR gather — one wave per dst, single pass.
// Edge ids loaded VECTORIZED per 64-chunk, broadcast via v_readlane;
// 4 edges per iteration so 12 independent global loads are in flight.
// ---------------------------------------------------------------------------
__global__ __launch_bounds__(256) void gather2_kernel(
    DirP P0, DirP P1,
    const int* __restrict__ rowptr, const int* __restrict__ eord,
    const float* __restrict__ exbuf, const float* __restrict__ V,
    float* __restrict__ agg_a, float* __restrict__ agg_b, int half)
{
    __shared__ float WtS[TDIM * HIDD];   // 16 KB, natural [k][d]
    __shared__ float uS[4][HIDD];
    int bi = blockIdx.x;
    const int dir = bi >= half;
    bi -= dir * half;
    const DirP& P = dir ? P1 : P0;
    rowptr += dir * (N_NODES + 8);
    eord   += (long)dir * NE;
    exbuf  += (long)dir * NE * 4;
    V      += (long)dir * N_NODES * HIDD;
    float* agg = dir ? agg_b : agg_a;

    const int t = threadIdx.x;
    #pragma unroll
    for (int i = 0; i < 4; ++i)
        *(float4*)&WtS[(t + i * 256) * 4] = *(const float4*)&P.Wt[(t + i * 256) * 4];
    __syncthreads();

    const int w = t >> 6, l = t & 63;
    const int dst = bi * 4 + w;                      // exact: 12500*4 = 50000
    const int h = l >> 4, d0 = 2 * l, k0 = d0 & 31;
    const int beg = rowptr[dst], end = rowptr[dst + 1];

    float s = 0.f, a0 = 0.f, a1 = 0.f, u0 = 0.f, u1 = 0.f;

    for (int cb = beg; cb < end; cb += 64) {
        const int m = min(64, end - cb);
        int e_v = 0, s_v = 0;
        if (l < m) {
            e_v = eord[cb + l];                       // coalesced
            s_v = P.ei[e_v];                          // gather, but vector
        }
        int i = 0;
        #pragma unroll 1
        for (; i + 4 <= m; i += 4) {
            const int ea = __builtin_amdgcn_readlane(e_v, i);
            const int eb2 = __builtin_amdgcn_readlane(e_v, i + 1);
            const int ec = __builtin_amdgcn_readlane(e_v, i + 2);
            const int ed = __builtin_amdgcn_readlane(e_v, i + 3);
            const int sa = __builtin_amdgcn_readlane(s_v, i);
            const int sb = __builtin_amdgcn_readlane(s_v, i + 1);
            const int sc = __builtin_amdgcn_readlane(s_v, i + 2);
            const int sd = __builtin_amdgcn_readlane(s_v, i + 3);
            const float  xa = exbuf[ea * 4 + h];
            const float  xb = exbuf[eb2 * 4 + h];
            const float  xc = exbuf[ec * 4 + h];
            const float  xd = exbuf[ed * 4 + h];
            const float2 va = *(const float2*)&V[(long)sa * HIDD + d0];
            const float2 vb = *(const float2*)&V[(long)sb * HIDD + d0];
            const float2 vc = *(const float2*)&V[(long)sc * HIDD + d0];
            const float2 vd = *(const float2*)&V[(long)sd * HIDD + d0];
            const float2 ta = *(const float2*)&P.tfeat[(long)ea * TDIM + k0];
            const float2 tb = *(const float2*)&P.tfeat[(long)eb2 * TDIM + k0];
            const float2 tc = *(const float2*)&P.tfeat[(long)ec * TDIM + k0];
            const float2 td = *(const float2*)&P.tfeat[(long)ed * TDIM + k0];
            s  += xa;            s  += xb;            s  += xc;            s  += xd;
            a0 += xa * va.x;     a0 += xb * vb.x;     a0 += xc * vc.x;     a0 += xd * vd.x;
            a1 += xa * va.y;     a1 += xb * vb.y;     a1 += xc * vc.y;     a1 += xd * vd.y;
            u0 += xa * ta.x;     u0 += xb * tb.x;     u0 += xc * tc.x;     u0 += xd * td.x;
            u1 += xa * ta.y;     u1 += xb * tb.y;     u1 += xc * tc.y;     u1 += xd * td.y;
        }
        #pragma unroll 1
        for (; i < m; ++i) {
            const int e   = __builtin_amdgcn_readlane(e_v, i);
            const int src = __builtin_amdgcn_readlane(s_v, i);
            const float  ex = exbuf[e * 4 + h];
            const float2 vv = *(const float2*)&V[(long)src * HIDD + d0];
            const float2 tk = *(const float2*)&P.tfeat[(long)e * TDIM + k0];
            s  += ex;
            a0 += ex * vv.x;  a1 += ex * vv.y;
            u0 += ex * tk.x;  u1 += ex * tk.y;
        }
    }
    *(float2*)&uS[w][d0] = make_float2(u0, u1);      // (h, k0) lives at idx d0
    __syncthreads();

    const float inv = 1.f / (s + 1e-16f);
    float t0 = 0.f, t1 = 0.f;
    #pragma unroll
    for (int k = 0; k < TDIM; ++k) {
        const float uu = uS[w][h * 32 + k];
        const float2 wv = *(const float2*)&WtS[k * HIDD + d0];
        t0 += uu * wv.x;
        t1 += uu * wv.y;
    }
    *(float2*)&agg[(long)dst * HIDD + d0] =
        make_float2((a0 + t0) * inv, (a1 + t1) * inv);
}

// ---------------------------------------------------------------------------
// Kernel D (fused user+item): out = LN(h + agg@Wout + bout)*lnw + lnb
// Dual-operand LDS staging with W swizzle, no prefetch (R10 spill lesson).
// ---------------------------------------------------------------------------
__global__ __launch_bounds__(256) void out_kernel(
    const float* __restrict__ agg_u, const float* __restrict__ agg_i,
    const float* __restrict__ h_u,   const float* __restrict__ h_i,
    const float* __restrict__ Wo_u,  const float* __restrict__ Wo_i,
    const float* __restrict__ bo_u,  const float* __restrict__ bo_i,
    const float* __restrict__ lw_u,  const float* __restrict__ lw_i,
    const float* __restrict__ lb_u,  const float* __restrict__ lb_i,
    float* __restrict__ out, int nblk)
{
    __shared__ float ag[128][32];        // 16 KB
    __shared__ float wl[32][HIDD];       // 16 KB
    const int dir = blockIdx.x >= nblk;
    const int b   = blockIdx.x - dir * nblk;
    const float* agg  = dir ? agg_i : agg_u;
    const float* hx   = dir ? h_i   : h_u;
    const float* Wout = dir ? Wo_i  : Wo_u;
    const float* bout = dir ? bo_i  : bo_u;
    const float* lnw  = dir ? lw_i  : lw_u;
    const float* lnb  = dir ? lb_i  : lb_u;
    float* outp = out + (long)dir * N_NODES * HIDD;

    const int t = threadIdx.x;
    const int g = t >> 4, q = t & 15;
    const int c0 = q * 8;
    const int l = t & 63;
    const int nb = b * 128;

    float acc[8][8];
    #pragma unroll
    for (int a = 0; a < 8; ++a)
        #pragma unroll
        for (int bb = 0; bb < 8; ++bb) acc[a][bb] = 0.f;

    #pragma unroll 1
    for (int kc = 0; kc < 4; ++kc) {
        stage_x32(ag, agg, nb, kc, t, N_NODES);
        stage_w32(wl, Wout, kc, t);
        __syncthreads();
        gemm_chunk(ag, wl, g, c0, acc);
        __syncthreads();
    }

    const float4 B0 = *(const float4*)&bout[c0], B1 = *(const float4*)&bout[c0+4];
    const float4 G0 = *(const float4*)&lnw[c0],  G1 = *(const float4*)&lnw[c0+4];
    const float4 L0 = *(const float4*)&lnb[c0],  L1 = *(const float4*)&lnb[c0+4];
    const float bo[8] = {B0.x,B0.y,B0.z,B0.w,B1.x,B1.y,B1.z,B1.w};
    const float gw[8] = {G0.x,G0.y,G0.z,G0.w,G1.x,G1.y,G1.z,G1.w};
    const float gb[8] = {L0.x,L0.y,L0.z,L0.w,L1.x,L1.y,L1.z,L1.w};

    #pragma unroll
    for (int nn = 0; nn < 8; ++nn) {
        const int node = nb + g * 8 + nn;
        const bool valid = node < N_NODES;
        float y[8];
        float4 H0 = make_float4(0,0,0,0), H1 = make_float4(0,0,0,0);
        if (valid) {
            H0 = *(const float4*)&hx[(long)node * HIDD + c0];
            H1 = *(const float4*)&hx[(long)node * HIDD + c0 + 4];
        }
        const float hv[8] = {H0.x,H0.y,H0.z,H0.w,H1.x,H1.y,H1.z,H1.w};
        float s1 = 0.f, s2 = 0.f;
        #pragma unroll
        for (int j = 0; j < 8; ++j) {
            y[j] = hv[j] + acc[nn][j] + bo[j];
            s1 += y[j];
            s2 += y[j] * y[j];
        }
        s1 += __shfl_down(s1, 8, 16); s2 += __shfl_down(s2, 8, 16);
        s1 += __shfl_down(s1, 4, 16); s2 += __shfl_down(s2, 4, 16);
        s1 += __shfl_down(s1, 2, 16); s2 += __shfl_down(s2, 2, 16);
        s1 += __shfl_down(s1, 1, 16); s2 += __shfl_down(s2, 1, 16);
        s1 = __shfl(s1, l & ~15);
        s2 = __shfl(s2, l & ~15);
        const float mu  = s1 * (1.f / 128.f);
        const float var = s2 * (1.f / 128.f) - mu * mu;
        const float inv = rsqrtf(var + 1e-5f);
        if (valid) {
            float o[8];
            #pragma unroll
            for (int j = 0; j < 8; ++j) o[j] = (y[j] - mu) * inv * gw[j] + gb[j];
            *(float4*)&outp[(long)node * HIDD + c0]     = make_float4(o[0],o[1],o[2],o[3]);
            *(float4*)&outp[(long)node * HIDD + c0 + 4] = make_float4(o[4],o[5],o[6],o[7]);
        }
    }
}

// ---------------------------------------------------------------------------
extern "C" void kernel_launch(void* const* d_in, const int* in_sizes, int n_in,
                              void* d_out, int out_size, void* d_ws, size_t ws_size,
                              hipStream_t stream)
{
    const float* h_user    = (const float*)d_in[0];
    const float* h_item    = (const float*)d_in[1];
    const int*   ei_ui     = (const int*)d_in[2];
    const float* t_ui      = (const float*)d_in[3];
    const int*   ei_iu     = (const int*)d_in[4];
    const float* t_iu      = (const float*)d_in[5];
    const float* W_src_ui  = (const float*)d_in[6];
    const float* W_dst_ui  = (const float*)d_in[7];
    const float* W_temp_ui = (const float*)d_in[8];
    const float* W_val_ui  = (const float*)d_in[9];
    const float* att_ui    = (const float*)d_in[10];
    const float* W_src_iu  = (const float*)d_in[11];
    const float* W_dst_iu  = (const float*)d_in[12];
    const float* W_temp_iu = (const float*)d_in[13];
    const float* W_val_iu  = (const float*)d_in[14];
    const float* att_iu    = (const float*)d_in[15];
    const float* Wout_user = (const float*)d_in[16];
    const float* bout_user = (const float*)d_in[17];
    const float* Wout_item = (const float*)d_in[18];
    const float* bout_item = (const float*)d_in[19];
    const float* lnw_user  = (const float*)d_in[20];
    const float* lnb_user  = (const float*)d_in[21];
    const float* lnw_item  = (const float*)d_in[22];
    const float* lnb_item  = (const float*)d_in[23];

    DirP P0, P1;
    P0.xsrc = h_user; P0.xdst = h_item; P0.Ws = W_src_ui; P0.Wd = W_dst_ui;
    P0.Wv = W_val_ui; P0.att = att_ui; P0.tfeat = t_ui; P0.Wt = W_temp_ui;
    P0.ei = ei_ui;
    P1.xsrc = h_item; P1.xdst = h_user; P1.Ws = W_src_iu; P1.Wd = W_dst_iu;
    P1.Wv = W_val_iu; P1.att = att_iu; P1.tfeat = t_iu; P1.Wt = W_temp_iu;
    P1.ei = ei_iu;

    const int edgeBlocks  = (NE + 255) / 256;         // 1954
    const int logitBlocks = (NE + 127) / 128;         // 3907
    const int dstBlocks   = N_NODES / 4;              // 12500
    const int projBlocks  = (N_NODES + 127) / 128;    // 391
    const int NB3         = 3 * projBlocks;           // 1173

    // Merged-path workspace need (bytes):
    // floats: agg 2*N*H, V 2*N*H, sj 2*N*4, si 2*N*4, exbuf 2*NE*4
    // ints:   rowptr 2*(N+8), cnt 2*N, eord 2*NE
    const size_t needMerged =
        sizeof(float) * (4L * N_NODES * HIDD + 4L * N_NODES * 4 + 2L * NE * 4) +
        sizeof(int)   * (2L * (N_NODES + 8) + 2L * N_NODES + 2L * NE) + 4096;
    const bool merged = ws_size >= needMerged;

    float* agg_item = (float*)d_ws;
    float* agg_user = agg_item + (long)N_NODES * HIDD;
    float* V        = agg_user + (long)N_NODES * HIDD;
    float* sj, *si, *exbuf;
    int *rowptr, *cnt, *eord;

    if (merged) {
        sj     = V + 2L * N_NODES * HIDD;
        si     = sj + 2L * N_NODES * 4;
        exbuf  = si + 2L * N_NODES * 4;
        rowptr = (int*)(exbuf + 2L * NE * 4);
    } else {
        sj     = V + (long)N_NODES * HIDD;
        si     = sj + (long)N_NODES * 4;
        exbuf  = si + (long)N_NODES * 4;
        rowptr = (int*)(exbuf + (long)NE * 4);
    }
    cnt  = rowptr + 2 * (N_NODES + 8);
    eord = cnt + 2 * N_NODES;

    // --- CSR build for BOTH directions (identical in both paths) ---
    hipMemsetAsync(cnt, 0, 2 * N_NODES * sizeof(int), stream);
    count2_kernel<<<2 * edgeBlocks, 256, 0, stream>>>(ei_ui + NE, ei_iu + NE, cnt);
    scan2_kernel<<<2, SCAN_T, 0, stream>>>(cnt, rowptr);
    hipMemsetAsync(cnt, 0, 2 * N_NODES * sizeof(int), stream);
    scatter2_kernel<<<2 * edgeBlocks, 256, 0, stream>>>(
        ei_ui + NE, ei_iu + NE, rowptr, cnt, eord);

    if (merged) {
        // Both directions per phase in one launch: deep grids, 3 fewer gaps.
        node_proj2_kernel<<<2 * NB3, 256, 0, stream>>>(P0, P1, sj, si, V, NB3);
        edge_logits2_kernel<<<2 * logitBlocks, 256, 0, stream>>>(
            P0, P1, sj, si, exbuf, logitBlocks);
        gather2_kernel<<<2 * dstBlocks, 256, 0, stream>>>(
            P0, P1, rowptr, eord, exbuf, V, agg_item, agg_user, dstBlocks);
    } else {
        // R11 sequential schedule (dir=0 inside kernels; buffers reused).
        for (int d = 0; d < 2; ++d) {
            const DirP& P = d == 0 ? P0 : P1;
            float* agg = d == 0 ? agg_item : agg_user;
            node_proj2_kernel<<<NB3, 256, 0, stream>>>(P, P, sj, si, V, NB3);
            edge_logits2_kernel<<<logitBlocks, 256, 0, stream>>>(
                P, P, sj, si, exbuf, logitBlocks);
            gather2_kernel<<<dstBlocks, 256, 0, stream>>>(
                P, P, rowptr + d * (N_NODES + 8), eord + (long)d * NE,
                exbuf, V, agg, agg, dstBlocks);
        }
    }

    out_kernel<<<2 * projBlocks, 256, 0, stream>>>(
        agg_user, agg_item, h_user, h_item,
        Wout_user, Wout_item, bout_user, bout_item,
        lnw_user, lnw_item, lnb_user, lnb_item,
        (float*)d_out, projBlocks);
}

// Round 13
// 797.239 us; speedup vs baseline: 1.0080x; 1.0080x over previous
//
#include <hip/hip_runtime.h>

#define N_NODES 50000
#define NE      500000
#define HIDD    128
#define TDIM    32

__device__ __forceinline__ float leaky(float z) { return z >= 0.f ? z : 0.2f * z; }

// Per-direction pointer bundle (passed by value to kernels).
struct DirP {
    const float *xsrc, *xdst, *Ws, *Wd, *Wv, *att, *tfeat, *Wt;
    const int* ei;
};

// ---------------------------------------------------------------------------
// R13 GEMM core: 128 rows/block, 8x8 tile/thread, K chunked by 16 with
// DOUBLE-BUFFERED async staging via global_load_lds (no VGPR round trip —
// R10's register prefetch spilled; this doesn't touch VGPRs at all).
// LDS is LINEAR (gll writes base+lane*16); the conflict-avoidance swizzles
// are baked into the per-lane GLOBAL source address (m173 pattern):
//  * X: lds[row][pq] <- x[row][kc*16 + (pq ^ ((row>>3)&3))*4]; gemm reads
//    quad (kq ^ (g&3)) -> 4 g-groups hit 4 distinct quads, broadcast, free.
//  * W: even/odd-quad split baked in source: lds phys quad p <- src quad
//    ((p&15)<<1)|(p>>4); gemm reads wl[k][c0>>1] / wl[k][64+(c0>>1)] at
//    16B lane stride (2-way = free).
// Schedule per chunk: issue gll(k+1 -> buf^1) ; FMA(k, buf) ; barrier
// (vmcnt(0) drain lands after ~2048 cyc of FMA cover) — m97 structure.
// Plain __launch_bounds__(256) (R7: min-waves arg clamps VGPR -> spill).
// ---------------------------------------------------------------------------
typedef const __attribute__((address_space(1))) void as1_void;
typedef __attribute__((address_space(3))) void       as3_void;

__device__ __forceinline__ void gll16(const float* g, float* l)
{
    __builtin_amdgcn_global_load_lds((as1_void*)g, (as3_void*)l, 16, 0, 0);
}

// X: 128 rows x 16 floats (one K=16 chunk). 512 quads, 2 per thread.
__device__ __forceinline__ void stage_x16(float* xs, const float* x,
                                          int nb, int kc, int t)
{
    #pragma unroll
    for (int i = 0; i < 2; ++i) {
        int idx = t + i * 256;              // 0..511 quads
        int row = idx >> 2, pq = idx & 3;
        int sq = pq ^ ((row >> 3) & 3);
        int rg = nb + row; rg = rg < N_NODES ? rg : N_NODES - 1;  // clamp OOB
        gll16(&x[(long)rg * HIDD + kc * 16 + sq * 4], xs + idx * 4);
    }
}

// W: 16 rows x 128 floats. 512 quads, 2 per thread, even/odd split in src.
__device__ __forceinline__ void stage_w16(float* wl, const float* W,
                                          int kc, int t)
{
    #pragma unroll
    for (int i = 0; i < 2; ++i) {
        int idx = t + i * 256;              // 0..511 quads
        int row = idx >> 5, p = idx & 31;
        int sq = ((p & 15) << 1) | (p >> 4);
        gll16(&W[(long)(kc * 16 + row) * HIDD + sq * 4], wl + idx * 4);
    }
}

__device__ __forceinline__ void gemm_chunk16(const float (*xs)[16],
                                             const float (*wl)[HIDD],
                                             int g, int c0, float acc[8][8])
{
    const int wq = c0 >> 1;                 // phys float offset of even quad
    #pragma unroll 1
    for (int kq = 0; kq < 4; ++kq) {
        float4 xv[8];
        const int col = ((kq ^ (g & 3)) << 2);
        #pragma unroll
        for (int nn = 0; nn < 8; ++nn)
            xv[nn] = *(const float4*)&xs[g * 8 + nn][col];
        #pragma unroll
        for (int kk = 0; kk < 4; ++kk) {
            const float4 wa = *(const float4*)&wl[kq * 4 + kk][wq];
            const float4 wb = *(const float4*)&wl[kq * 4 + kk][64 + wq];
            const float wv[8] = {wa.x, wa.y, wa.z, wa.w, wb.x, wb.y, wb.z, wb.w};
            #pragma unroll
            for (int nn = 0; nn < 8; ++nn) {
                const float xk = (kk == 0) ? xv[nn].x : (kk == 1) ? xv[nn].y
                               : (kk == 2) ? xv[nn].z : xv[nn].w;
                #pragma unroll
                for (int j = 0; j < 8; ++j) acc[nn][j] += xk * wv[j];
            }
        }
    }
}

// Per-head attention reduction: p = sum_c leaky(proj[c])*att[h][c&31],
// reduced over the 4 threads (q&3) sharing head h. Writer: q%4==0.
__device__ __forceinline__ void att_reduce_store(
    float acc[8][8], const float* __restrict__ att, int off,
    int nb, int g, int q, int h, float* __restrict__ outp)
{
    const float* ap = att + h * 96 + off + 8 * (q & 3);
    const float4 A0 = *(const float4*)ap, A1 = *(const float4*)(ap + 4);
    const float av[8] = {A0.x, A0.y, A0.z, A0.w, A1.x, A1.y, A1.z, A1.w};
    #pragma unroll
    for (int nn = 0; nn < 8; ++nn) {
        float p = 0.f;
        #pragma unroll
        for (int j = 0; j < 8; ++j) p += leaky(acc[nn][j]) * av[j];
        p += __shfl_down(p, 2, 4);
        p += __shfl_down(p, 1, 4);
        const int node = nb + g * 8 + nn;
        if ((q & 3) == 0 && node < N_NODES) outp[node * 4 + h] = p;
    }
}

// ---------------------------------------------------------------------------
// Kernel A: per-node projections (sj, si, V). Grid = half (seq) or 2*half.
// Within a dir: block bi -> m = bi%3 in {Ws->sj, Wv->V, Wd->si}, b = bi/3.
// ---------------------------------------------------------------------------
__global__ __launch_bounds__(256) void node_proj2_kernel(
    DirP P0, DirP P1,
    float* __restrict__ sj, float* __restrict__ si, float* __restrict__ V,
    int half)
{
    __shared__ float xs[2][128][16];      // 16 KB (double-buffered)
    __shared__ float wl[2][16][HIDD];     // 16 KB (double-buffered)
    int bi = blockIdx.x;
    const int dir = bi >= half;
    bi -= dir * half;
    const DirP& P = dir ? P1 : P0;
    sj += (long)dir * N_NODES * 4;
    si += (long)dir * N_NODES * 4;
    V  += (long)dir * N_NODES * HIDD;

    const int m = bi % 3;                 // 0:Ws->sj 1:Wv->V 2:Wd->si
    const int b = bi / 3;
    const int t = threadIdx.x;
    const int g = t >> 4, q = t & 15;
    const int c0 = q * 8, h = q >> 2;
    const int nb = b * 128;

    const float* x = (m == 2) ? P.xdst : P.xsrc;
    const float* W = (m == 0) ? P.Ws : (m == 1) ? P.Wv : P.Wd;

    float acc[8][8];
    #pragma unroll
    for (int a = 0; a < 8; ++a)
        #pragma unroll
        for (int bb = 0; bb < 8; ++bb) acc[a][bb] = 0.f;

    stage_x16(&xs[0][0][0], x, nb, 0, t);
    stage_w16(&wl[0][0][0], W, 0, t);
    __syncthreads();

    int cur = 0;
    #pragma unroll 1
    for (int kc = 0; kc < 8; ++kc) {
        if (kc < 7) {                     // async prefetch under the FMAs
            stage_x16(&xs[cur ^ 1][0][0], x, nb, kc + 1, t);
            stage_w16(&wl[cur ^ 1][0][0], W, kc + 1, t);
        }
        gemm_chunk16(xs[cur], wl[cur], g, c0, acc);
        __syncthreads();
        cur ^= 1;
    }

    if (m == 1) {
        #pragma unroll
        for (int nn = 0; nn < 8; ++nn) {
            const int node = nb + g * 8 + nn;
            if (node < N_NODES) {
                *(float4*)&V[(long)node * HIDD + c0] =
                    make_float4(acc[nn][0], acc[nn][1], acc[nn][2], acc[nn][3]);
                *(float4*)&V[(long)node * HIDD + c0 + 4] =
                    make_float4(acc[nn][4], acc[nn][5], acc[nn][6], acc[nn][7]);
            }
        }
    } else if (m == 0) {
        att_reduce_store(acc, P.att, 0, nb, g, q, h, sj);
    } else {
        att_reduce_store(acc, P.att, 32, nb, g, q, h, si);
    }
}

// ---------------------------------------------------------------------------
// CSR build: both directions in one pass each. R13: scan zeroes cnt after
// reading (removes the second memset dispatch).
// ---------------------------------------------------------------------------
__global__ __launch_bounds__(256) void count2_kernel(
    const int* __restrict__ ed0, const int* __restrict__ ed1,
    int* __restrict__ cnt)
{
    const int EB = (NE + 255) / 256;
    const int b = blockIdx.x;
    const int dir = b >= EB;
    const int e = (b - dir * EB) * 256 + threadIdx.x;
    const int* ed = dir ? ed1 : ed0;
    if (e < NE) atomicAdd(&cnt[dir * N_NODES + ed[e]], 1);
}

#define SCAN_T 1024
#define SCAN_CHUNK 49
__global__ __launch_bounds__(1024) void scan2_kernel(
    int* __restrict__ cnt, int* __restrict__ rowptr)
{
    __shared__ int part[SCAN_T];
    const int dir = blockIdx.x;
    int* c = cnt + dir * N_NODES;
    int* rp = rowptr + dir * (N_NODES + 8);
    const int t = threadIdx.x;
    const int b = t * SCAN_CHUNK;
    const int e = min(b + SCAN_CHUNK, N_NODES);
    int s = 0;
    for (int i = b; i < e; ++i) s += c[i];
    part[t] = s;
    __syncthreads();
    for (int off = 1; off < SCAN_T; off <<= 1) {
        int v = (t >= off) ? part[t - off] : 0;
        __syncthreads();
        part[t] += v;
        __syncthreads();
    }
    int run = (t > 0) ? part[t - 1] : 0;
    for (int i = b; i < e; ++i) { rp[i] = run; run += c[i]; c[i] = 0; }
    if (t == SCAN_T - 1) rp[N_NODES] = part[SCAN_T - 1];
}

__global__ __launch_bounds__(256) void scatter2_kernel(
    const int* __restrict__ ed0, const int* __restrict__ ed1,
    const int* __restrict__ rowptr, int* __restrict__ cursor,
    int* __restrict__ eord)
{
    const int EB = (NE + 255) / 256;
    const int b = blockIdx.x;
    const int dir = b >= EB;
    const int e = (b - dir * EB) * 256 + threadIdx.x;
    if (e < NE) {
        const int* ed = dir ? ed1 : ed0;
        const int d = ed[e];
        const int pos = rowptr[dir * (N_NODES + 8) + d]
                      + atomicAdd(&cursor[dir * N_NODES + d], 1);
        eord[dir * NE + pos] = e;
    }
}

// ---------------------------------------------------------------------------
// Kernel B: per-edge logits + exp. Wt staged once (even/odd swizzle, VGPR
// path — one-time stage, not worth gll). 128 edges/block, 8x8/thread, K=32.
// ---------------------------------------------------------------------------
__global__ __launch_bounds__(256, 4) void edge_logits2_kernel(
    DirP P0, DirP P1,
    const float* __restrict__ sj, const float* __restrict__ si,
    float* __restrict__ exbuf, int half)
{
    __shared__ float ts[128][TDIM];       // 16 KB
    __shared__ float wt[TDIM][HIDD];      // 16 KB
    int bi = blockIdx.x;
    const int dir = bi >= half;
    bi -= dir * half;
    const DirP& P = dir ? P1 : P0;
    sj    += (long)dir * N_NODES * 4;
    si    += (long)dir * N_NODES * 4;
    exbuf += (long)dir * NE * 4;

    const int t = threadIdx.x;
    const int g = t >> 4, q = t & 15;
    const int c0 = q * 8, h = q >> 2;
    const int wq = c0 >> 1;
    const int eb = bi * 128;

    #pragma unroll
    for (int i = 0; i < 4; ++i) {
        int idx = t + i * 256;
        int row = idx >> 3, c4 = idx & 7;
        int col = (c4 ^ ((row >> 3) & 7)) << 2;
        float4 v = make_float4(0.f, 0.f, 0.f, 0.f);
        if (eb + row < NE)
            v = *(const float4*)&P.tfeat[(long)(eb + row) * TDIM + c4 * 4];
        *(float4*)&ts[row][col] = v;
    }
    #pragma unroll
    for (int i = 0; i < 4; ++i) {
        int idx = t + i * 256;              // 0..1023 quads
        int row = idx >> 5, c4 = idx & 31;
        int p = ((c4 & 1) << 4) | (c4 >> 1);
        *(float4*)&wt[row][p * 4] =
            *(const float4*)&P.Wt[(long)row * HIDD + c4 * 4];
    }
    __syncthreads();

    float acc[8][8];
    #pragma unroll
    for (int a = 0; a < 8; ++a)
        #pragma unroll
        for (int b = 0; b < 8; ++b) acc[a][b] = 0.f;

    #pragma unroll 1
    for (int k4 = 0; k4 < 8; ++k4) {
        float4 xv[8];
        const int col = ((k4 ^ (g & 7)) << 2);
        #pragma unroll
        for (int nn = 0; nn < 8; ++nn)
            xv[nn] = *(const float4*)&ts[g * 8 + nn][col];
        #pragma unroll
        for (int kk = 0; kk < 4; ++kk) {
            const float4 wa = *(const float4*)&wt[k4 * 4 + kk][wq];
            const float4 wb = *(const float4*)&wt[k4 * 4 + kk][64 + wq];
            const float wv[8] = {wa.x, wa.y, wa.z, wa.w, wb.x, wb.y, wb.z, wb.w};
            #pragma unroll
            for (int nn = 0; nn < 8; ++nn) {
                const float xk = (kk == 0) ? xv[nn].x : (kk == 1) ? xv[nn].y
                               : (kk == 2) ? xv[nn].z : xv[nn].w;
                #pragma unroll
                for (int j = 0; j < 8; ++j) acc[nn][j] += xk * wv[j];
            }
        }
    }

    const float* ap = P.att + h * 96 + 64 + 8 * (q & 3);
    const float4 A0 = *(const float4*)ap, A1 = *(const float4*)(ap + 4);
    const float av[8] = {A0.x, A0.y, A0.z, A0.w, A1.x, A1.y, A1.z, A1.w};
    float st[8];
    #pragma unroll
    for (int nn = 0; nn < 8; ++nn) {
        float p = 0.f;
        #pragma unroll
        for (int j = 0; j < 8; ++j) p += leaky(acc[nn][j]) * av[j];
        p += __shfl_down(p, 2, 4);
        p += __shfl_down(p, 1, 4);
        st[nn] = p;
    }
    if ((q & 3) == 0) {
        #pragma unroll
        for (int nn = 0; nn < 8; ++nn) {
            const int e = eb + g * 8 + nn;
            if (e < NE) {
                const int src = P.ei[e], dst = P.ei[NE + e];
                exbuf[e * 4 + h] =
                    __expf(sj[src * 4 + h] + si[dst * 4 + h] + st[nn]);
            }
        }
    }
}

// ---------------------------------------------------------------------------
// Kernel C: CSR gather — one wave per dst, single pass.
// Edge ids loaded VECTORIZED per 64-chunk, broadcast via v_readlane;
// 4 edges per iteration so 12 independent global loads are in flight.
// ---------------------------------------------------------------------------
__global__ __launch_bounds__(256) void gather2_kernel(
    DirP P0, DirP P1,
    const int* __restrict__ rowptr, const int* __restrict__ eord,
    const float* __restrict__ exbuf, const float* __restrict__ V,
    float* __restrict__ agg_a, float* __restrict__ agg_b, int half)
{
    __shared__ float WtS[TDIM * HIDD];   // 16 KB, natural [k][d]
    __shared__ float uS[4][HIDD];
    int bi = blockIdx.x;
    const int dir = bi >= half;
    bi -= dir * half;
    const DirP& P = dir ? P1 : P0;
    rowptr += dir * (N_NODES + 8);
    eord   += (long)dir * NE;
    exbuf  += (long)dir * NE * 4;
    V      += (long)dir * N_NODES * HIDD;
    float* agg = dir ? agg_b : agg_a;

    const int t = threadIdx.x;
    #pragma unroll
    for (int i = 0; i < 4; ++i)
        *(float4*)&WtS[(t + i * 256) * 4] = *(const float4*)&P.Wt[(t + i * 256) * 4];
    __syncthreads();

    const int w = t >> 6, l = t & 63;
    const int dst = bi * 4 + w;                      // exact: 12500*4 = 50000
    const int h = l >> 4, d0 = 2 * l, k0 = d0 & 31;
    const int beg = rowptr[dst], end = rowptr[dst + 1];

    float s = 0.f, a0 = 0.f, a1 = 0.f, u0 = 0.f, u1 = 0.f;

    for (int cb = beg; cb < end; cb += 64) {
        const int m = min(64, end - cb);
        int e_v = 0, s_v = 0;
        if (l < m) {
            e_v = eord[cb + l];                       // coalesced
            s_v = P.ei[e_v];                          // gather, but vector
        }
        int i = 0;
        #pragma unroll 1
        for (; i + 4 <= m; i += 4) {
            const int ea = __builtin_amdgcn_readlane(e_v, i);
            const int eb2 = __builtin_amdgcn_readlane(e_v, i + 1);
            const int ec = __builtin_amdgcn_readlane(e_v, i + 2);
            const int ed = __builtin_amdgcn_readlane(e_v, i + 3);
            const int sa = __builtin_amdgcn_readlane(s_v, i);
            const int sb = __builtin_amdgcn_readlane(s_v, i + 1);
            const int sc = __builtin_amdgcn_readlane(s_v, i + 2);
            const int sd = __builtin_amdgcn_readlane(s_v, i + 3);
            const float  xa = exbuf[ea * 4 + h];
            const float  xb = exbuf[eb2 * 4 + h];
            const float  xc = exbuf[ec * 4 + h];
            const float  xd = exbuf[ed * 4 + h];
            const float2 va = *(const float2*)&V[(long)sa * HIDD + d0];
            const float2 vb = *(const float2*)&V[(long)sb * HIDD + d0];
            const float2 vc = *(const float2*)&V[(long)sc * HIDD + d0];
            const float2 vd = *(const float2*)&V[(long)sd * HIDD + d0];
            const float2 ta = *(const float2*)&P.tfeat[(long)ea * TDIM + k0];
            const float2 tb = *(const float2*)&P.tfeat[(long)eb2 * TDIM + k0];
            const float2 tc = *(const float2*)&P.tfeat[(long)ec * TDIM + k0];
            const float2 td = *(const float2*)&P.tfeat[(long)ed * TDIM + k0];
            s  += xa;            s  += xb;            s  += xc;            s  += xd;
            a0 += xa * va.x;     a0 += xb * vb.x;     a0 += xc * vc.x;     a0 += xd * vd.x;
            a1 += xa * va.y;     a1 += xb * vb.y;     a1 += xc * vc.y;     a1 += xd * vd.y;
            u0 += xa * ta.x;     u0 += xb * tb.x;     u0 += xc * tc.x;     u0 += xd * td.x;
            u1 += xa * ta.y;     u1 += xb * tb.y;     u1 += xc * tc.y;     u1 += xd * td.y;
        }
        #pragma unroll 1
        for (; i < m; ++i) {
            const int e   = __builtin_amdgcn_readlane(e_v, i);
            const int src = __builtin_amdgcn_readlane(s_v, i);
            const float  ex = exbuf[e * 4 + h];
            const float2 vv = *(const float2*)&V[(long)src * HIDD + d0];
            const float2 tk = *(const float2*)&P.tfeat[(long)e * TDIM + k0];
            s  += ex;
            a0 += ex * vv.x;  a1 += ex * vv.y;
            u0 += ex * tk.x;  u1 += ex * tk.y;
        }
    }
    *(float2*)&uS[w][d0] = make_float2(u0, u1);      // (h, k0) lives at idx d0
    __syncthreads();

    const float inv = 1.f / (s + 1e-16f);
    float t0 = 0.f, t1 = 0.f;
    #pragma unroll
    for (int k = 0; k < TDIM; ++k) {
        const float uu = uS[w][h * 32 + k];
        const float2 wv = *(const float2*)&WtS[k * HIDD + d0];
        t0 += uu * wv.x;
        t1 += uu * wv.y;
    }
    *(float2*)&agg[(long)dst * HIDD + d0] =
        make_float2((a0 + t0) * inv, (a1 + t1) * inv);
}

// ---------------------------------------------------------------------------
// Kernel D (fused user+item): out = LN(h + agg@Wout + bout)*lnw + lnb
// R13: K=16 double-buffered global_load_lds staging, as node_proj2.
// ---------------------------------------------------------------------------
__global__ __launch_bounds__(256) void out_kernel(
    const float* __restrict__ agg_u, const float* __restrict__ agg_i,
    const float* __restrict__ h_u,   const float* __restrict__ h_i,
    const float* __restrict__ Wo_u,  const float* __restrict__ Wo_i,
    const float* __restrict__ bo_u,  const float* __restrict__ bo_i,
    const float* __restrict__ lw_u,  const float* __restrict__ lw_i,
    const float* __restrict__ lb_u,  const float* __restrict__ lb_i,
    float* __restrict__ out, int nblk)
{
    __shared__ float ag[2][128][16];     // 16 KB
    __shared__ float wl[2][16][HIDD];    // 16 KB
    const int dir = blockIdx.x >= nblk;
    const int b   = blockIdx.x - dir * nblk;
    const float* agg  = dir ? agg_i : agg_u;
    const float* hx   = dir ? h_i   : h_u;
    const float* Wout = dir ? Wo_i  : Wo_u;
    const float* bout = dir ? bo_i  : bo_u;
    const float* lnw  = dir ? lw_i  : lw_u;
    const float* lnb  = dir ? lb_i  : lb_u;
    float* outp = out + (long)dir * N_NODES * HIDD;

    const int t = threadIdx.x;
    const int g = t >> 4, q = t & 15;
    const int c0 = q * 8;
    const int l = t & 63;
    const int nb = b * 128;

    float acc[8][8];
    #pragma unroll
    for (int a = 0; a < 8; ++a)
        #pragma unroll
        for (int bb = 0; bb < 8; ++bb) acc[a][bb] = 0.f;

    stage_x16(&ag[0][0][0], agg, nb, 0, t);
    stage_w16(&wl[0][0][0], Wout, 0, t);
    __syncthreads();

    int cur = 0;
    #pragma unroll 1
    for (int kc = 0; kc < 8; ++kc) {
        if (kc < 7) {
            stage_x16(&ag[cur ^ 1][0][0], agg, nb, kc + 1, t);
            stage_w16(&wl[cur ^ 1][0][0], Wout, kc + 1, t);
        }
        gemm_chunk16(ag[cur], wl[cur], g, c0, acc);
        __syncthreads();
        cur ^= 1;
    }

    const float4 B0 = *(const float4*)&bout[c0], B1 = *(const float4*)&bout[c0+4];
    const float4 G0 = *(const float4*)&lnw[c0],  G1 = *(const float4*)&lnw[c0+4];
    const float4 L0 = *(const float4*)&lnb[c0],  L1 = *(const float4*)&lnb[c0+4];
    const float bo[8] = {B0.x,B0.y,B0.z,B0.w,B1.x,B1.y,B1.z,B1.w};
    const float gw[8] = {G0.x,G0.y,G0.z,G0.w,G1.x,G1.y,G1.z,G1.w};
    const float gb[8] = {L0.x,L0.y,L0.z,L0.w,L1.x,L1.y,L1.z,L1.w};

    #pragma unroll
    for (int nn = 0; nn < 8; ++nn) {
        const int node = nb + g * 8 + nn;
        const bool valid = node < N_NODES;
        float y[8];
        float4 H0 = make_float4(0,0,0,0), H1 = make_float4(0,0,0,0);
        if (valid) {
            H0 = *(const float4*)&hx[(long)node * HIDD + c0];
            H1 = *(const float4*)&hx[(long)node * HIDD + c0 + 4];
        }
        const float hv[8] = {H0.x,H0.y,H0.z,H0.w,H1.x,H1.y,H1.z,H1.w};
        float s1 = 0.f, s2 = 0.f;
        #pragma unroll
        for (int j = 0; j < 8; ++j) {
            y[j] = hv[j] + acc[nn][j] + bo[j];
            s1 += y[j];
            s2 += y[j] * y[j];
        }
        s1 += __shfl_down(s1, 8, 16); s2 += __shfl_down(s2, 8, 16);
        s1 += __shfl_down(s1, 4, 16); s2 += __shfl_down(s2, 4, 16);
        s1 += __shfl_down(s1, 2, 16); s2 += __shfl_down(s2, 2, 16);
        s1 += __shfl_down(s1, 1, 16); s2 += __shfl_down(s2, 1, 16);
        s1 = __shfl(s1, l & ~15);
        s2 = __shfl(s2, l & ~15);
        const float mu  = s1 * (1.f / 128.f);
        const float var = s2 * (1.f / 128.f) - mu * mu;
        const float inv = rsqrtf(var + 1e-5f);
        if (valid) {
            float o[8];
            #pragma unroll
            for (int j = 0; j < 8; ++j) o[j] = (y[j] - mu) * inv * gw[j] + gb[j];
            *(float4*)&outp[(long)node * HIDD + c0]     = make_float4(o[0],o[1],o[2],o[3]);
            *(float4*)&outp[(long)node * HIDD + c0 + 4] = make_float4(o[4],o[5],o[6],o[7]);
        }
    }
}

// ---------------------------------------------------------------------------
extern "C" void kernel_launch(void* const* d_in, const int* in_sizes, int n_in,
                              void* d_out, int out_size, void* d_ws, size_t ws_size,
                              hipStream_t stream)
{
    const float* h_user    = (const float*)d_in[0];
    const float* h_item    = (const float*)d_in[1];
    const int*   ei_ui     = (const int*)d_in[2];
    const float* t_ui      = (const float*)d_in[3];
    const int*   ei_iu     = (const int*)d_in[4];
    const float* t_iu      = (const float*)d_in[5];
    const float* W_src_ui  = (const float*)d_in[6];
    const float* W_dst_ui  = (const float*)d_in[7];
    const float* W_temp_ui = (const float*)d_in[8];
    const float* W_val_ui  = (const float*)d_in[9];
    const float* att_ui    = (const float*)d_in[10];
    const float* W_src_iu  = (const float*)d_in[11];
    const float* W_dst_iu  = (const float*)d_in[12];
    const float* W_temp_iu = (const float*)d_in[13];
    const float* W_val_iu  = (const float*)d_in[14];
    const float* att_iu    = (const float*)d_in[15];
    const float* Wout_user = (const float*)d_in[16];
    const float* bout_user = (const float*)d_in[17];
    const float* Wout_item = (const float*)d_in[18];
    const float* bout_item = (const float*)d_in[19];
    const float* lnw_user  = (const float*)d_in[20];
    const float* lnb_user  = (const float*)d_in[21];
    const float* lnw_item  = (const float*)d_in[22];
    const float* lnb_item  = (const float*)d_in[23];

    DirP P0, P1;
    P0.xsrc = h_user; P0.xdst = h_item; P0.Ws = W_src_ui; P0.Wd = W_dst_ui;
    P0.Wv = W_val_ui; P0.att = att_ui; P0.tfeat = t_ui; P0.Wt = W_temp_ui;
    P0.ei = ei_ui;
    P1.xsrc = h_item; P1.xdst = h_user; P1.Ws = W_src_iu; P1.Wd = W_dst_iu;
    P1.Wv = W_val_iu; P1.att = att_iu; P1.tfeat = t_iu; P1.Wt = W_temp_iu;
    P1.ei = ei_iu;

    const int edgeBlocks  = (NE + 255) / 256;         // 1954
    const int logitBlocks = (NE + 127) / 128;         // 3907
    const int dstBlocks   = N_NODES / 4;              // 12500
    const int projBlocks  = (N_NODES + 127) / 128;    // 391
    const int NB3         = 3 * projBlocks;           // 1173

    const size_t needMerged =
        sizeof(float) * (4L * N_NODES * HIDD + 4L * N_NODES * 4 + 2L * NE * 4) +
        sizeof(int)   * (2L * (N_NODES + 8) + 2L * N_NODES + 2L * NE) + 4096;
    const bool merged = ws_size >= needMerged;

    float* agg_item = (float*)d_ws;
    float* agg_user = agg_item + (long)N_NODES * HIDD;
    float* V        = agg_user + (long)N_NODES * HIDD;
    float* sj, *si, *exbuf;
    int *rowptr, *cnt, *eord;

    if (merged) {
        sj     = V + 2L * N_NODES * HIDD;
        si     = sj + 2L * N_NODES * 4;
        exbuf  = si + 2L * N_NODES * 4;
        rowptr = (int*)(exbuf + 2L * NE * 4);
    } else {
        sj     = V + (long)N_NODES * HIDD;
        si     = sj + (long)N_NODES * 4;
        exbuf  = si + (long)N_NODES * 4;
        rowptr = (int*)(exbuf + (long)NE * 4);
    }
    cnt  = rowptr + 2 * (N_NODES + 8);
    eord = cnt + 2 * N_NODES;

    // --- CSR build for BOTH directions (scan zeroes cnt; one memset only) ---
    hipMemsetAsync(cnt, 0, 2 * N_NODES * sizeof(int), stream);
    count2_kernel<<<2 * edgeBlocks, 256, 0, stream>>>(ei_ui + NE, ei_iu + NE, cnt);
    scan2_kernel<<<2, SCAN_T, 0, stream>>>(cnt, rowptr);
    scatter2_kernel<<<2 * edgeBlocks, 256, 0, stream>>>(
        ei_ui + NE, ei_iu + NE, rowptr, cnt, eord);

    if (merged) {
        node_proj2_kernel<<<2 * NB3, 256, 0, stream>>>(P0, P1, sj, si, V, NB3);
        edge_logits2_kernel<<<2 * logitBlocks, 256, 0, stream>>>(
            P0, P1, sj, si, exbuf, logitBlocks);
        gather2_kernel<<<2 * dstBlocks, 256, 0, stream>>>(
            P0, P1, rowptr, eord, exbuf, V, agg_item, agg_user, dstBlocks);
    } else {
        for (int d = 0; d < 2; ++d) {
            const DirP& P = d == 0 ? P0 : P1;
            float* agg = d == 0 ? agg_item : agg_user;
            node_proj2_kernel<<<NB3, 256, 0, stream>>>(P, P, sj, si, V, NB3);
            edge_logits2_kernel<<<logitBlocks, 256, 0, stream>>>(
                P, P, sj, si, exbuf, logitBlocks);
            gather2_kernel<<<dstBlocks, 256, 0, stream>>>(
                P, P, rowptr + d * (N_NODES + 8), eord + (long)d * NE,
                exbuf, V, agg, agg, dstBlocks);
        }
    }

    out_kernel<<<2 * projBlocks, 256, 0, stream>>>(
        agg_user, agg_item, h_user, h_item,
        Wout_user, Wout_item, bout_user, bout_item,
        lnw_user, lnw_item, lnb_user, lnb_item,
        (float*)d_out, projBlocks);
}